// Round 3
// baseline (353.505 us; speedup 1.0000x reference)
//
#include <hip/hip_runtime.h>

constexpr int SEQ = 256;
constexpr int DIM = 1024;
constexpr float SCALE = 0.0625f;  // 1/sqrt(256)

typedef __attribute__((ext_vector_type(8))) short bf16x8;
typedef __attribute__((ext_vector_type(4))) float f32x4;
typedef unsigned short ushort_t;
typedef unsigned int uint_t;

__device__ __forceinline__ void gld_lds16(const void* g, void* l) {
  __builtin_amdgcn_global_load_lds(
      (const __attribute__((address_space(1))) unsigned int*)g,
      (__attribute__((address_space(3))) unsigned int*)l, 16, 0, 0);
}

__device__ __forceinline__ ushort_t f2bf(float f) {  // round-to-nearest-even
  uint_t u = __float_as_uint(f);
  return (ushort_t)((u + 0x7fffu + ((u >> 16) & 1u)) >> 16);
}

// ---------------- prep_a: A_bf[m][k] = bf16(x + pos), row-major [16384][1024] ----------
__global__ __launch_bounds__(256)
void prep_a(const float* __restrict__ x, const float* __restrict__ pos,
            ushort_t* __restrict__ Ab) {
  const size_t idx = ((size_t)blockIdx.x * 256 + threadIdx.x) * 8;
  const int m = (int)(idx >> 10), k = (int)(idx & 1023);
  float4 x0 = *(const float4*)(x + idx);
  float4 x1 = *(const float4*)(x + idx + 4);
  const float* pp = pos + ((size_t)(m & 255) << 10) + k;
  float4 p0 = *(const float4*)pp;
  float4 p1 = *(const float4*)(pp + 4);
  uint_t w0 = (uint_t)f2bf(x0.x + p0.x) | ((uint_t)f2bf(x0.y + p0.y) << 16);
  uint_t w1 = (uint_t)f2bf(x0.z + p0.z) | ((uint_t)f2bf(x0.w + p0.w) << 16);
  uint_t w2 = (uint_t)f2bf(x1.x + p1.x) | ((uint_t)f2bf(x1.y + p1.y) << 16);
  uint_t w3 = (uint_t)f2bf(x1.z + p1.z) | ((uint_t)f2bf(x1.w + p1.w) << 16);
  *(uint4*)&Ab[idx] = make_uint4(w0, w1, w2, w3);
}

// ---------------- pack_w: W[k][n] fp32 -> bf16 tiles [nb 12][kc 16][n 256][k 64] -------
__global__ __launch_bounds__(256)
void pack_w(const float* __restrict__ Wq, const float* __restrict__ Wk,
            const float* __restrict__ Wv, ushort_t* __restrict__ Bp) {
  const float* W = (blockIdx.z == 0) ? Wq : (blockIdx.z == 1) ? Wk : Wv;
  const int n  = blockIdx.x * 256 + threadIdx.x;
  const int k8 = blockIdx.y * 8;
  uint_t h[8];
#pragma unroll
  for (int i = 0; i < 8; ++i) h[i] = f2bf(W[(size_t)(k8 + i) * DIM + n]);
  uint_t hp[4];
#pragma unroll
  for (int j = 0; j < 4; ++j) hp[j] = h[2 * j] | (h[2 * j + 1] << 16);
  const int np = blockIdx.z * 1024 + n;
  const int nb = np >> 8, nl = np & 255;
  const int kc = k8 >> 6, kk = k8 & 63;
  size_t base = (((size_t)nb * 16 + kc) * 256 + nl) * 64 + kk;
  *(uint4*)&Bp[base] = make_uint4(hp[0], hp[1], hp[2], hp[3]);
}

// ---------------- qkv: 128x256 tile, BK=32, 8 waves (2x4), ring-3 LDS, 2 blocks/CU ----
// Per-wave output 64x64, acc[4][4] (64 VGPR) -> __launch_bounds__(512,4) targets 4
// waves/SIMD (16 waves/CU, 2 blocks co-resident) so barriers/staging latency hide via TLP.
// LDS 72 KiB: A ring3 [128][32] (8 KB each) + B ring3 [256][32] (16 KB each).
// Per K-tile t: barrier1 (stage(t) landed block-wide, via everyone's vmcnt at t-1) ->
// frag reads (8x ds_read_b128) -> lgkm0 -> barrier2 (reads done) -> stage(t+3) into
// buf[t%3] -> 16 MFMA -> vmcnt(6) (confirms own stage(t+1); 6 = stages t+2,t+3 in flight).
// 64-B LDS rows: chunk ^= (row>>1)&3 involution (global-source side + read side) -> 2-way
// bank aliasing only (free). Tail (t=29..31) peeled with exact vmcnt(3)/(0).
__global__ __launch_bounds__(512, 4)
void qkv_mfma(const ushort_t* __restrict__ Ab, const ushort_t* __restrict__ Bp,
              ushort_t* __restrict__ q_bf, ushort_t* __restrict__ k_bf,
              ushort_t* __restrict__ vT_bf) {
  const int nb = blockIdx.x;   // 0..11
  const int mb = blockIdx.y;   // 0..127
  const int tid = (int)threadIdx.x;
  const int wave = tid >> 6, lane = tid & 63;
  const int wr = wave >> 2, wc = wave & 3;
  const int l15 = lane & 15, quad = lane >> 4;

  __shared__ ushort_t smem[36864];  // A: r3*4096 ush; B: 12288 + r3*8192 ush (73728 B)

  // ---- staging maps (thread -> slot; phys chunk tid&3, fetch logical chunk ^((row>>1)&3))
  const int ar = tid >> 2, ap = tid & 3;
  const int al = ap ^ ((ar >> 1) & 3);                    // same formula for A and B op0/op1
  const ushort_t* a_src = Ab + ((size_t)(mb * 128 + ar) << 10) + al * 8;
  const ushort_t* b_src0 = Bp + ((size_t)(nb * 16) * 256 + ar) * 64 + al * 8;
  const ushort_t* b_src1 = b_src0 + 128 * 64;             // rows 128..255, same swizzle

#define STAGE(T, R3) do { \
    const size_t ka = (size_t)(T) * 32; \
    const size_t kb = (size_t)((T) >> 1) * 16384 + (size_t)((T) & 1) * 32; \
    gld_lds16(a_src + ka, smem + (R3) * 4096 + wave * 512); \
    gld_lds16(b_src0 + kb, smem + 12288 + (R3) * 8192 + wave * 512); \
    gld_lds16(b_src1 + kb, smem + 12288 + (R3) * 8192 + 4096 + wave * 512); \
  } while (0)

  // ---- fragment read offsets (bytes), loop-invariant
  int aofs[4], bofs[4];
#pragma unroll
  for (int m = 0; m < 4; ++m) {
    const int row = wr * 64 + m * 16 + l15;
    aofs[m] = row * 64 + ((quad ^ ((row >> 1) & 3)) * 16);
  }
#pragma unroll
  for (int j = 0; j < 4; ++j) {
    const int n = wc * 64 + j * 16 + l15;
    bofs[j] = n * 64 + ((quad ^ ((n >> 1) & 3)) * 16);
  }

  f32x4 acc[4][4] = {};
  bf16x8 af[4], bfr[4];

#define READS(R3) do { \
    const char* ab_ = (const char*)smem + (R3) * 8192; \
    const char* bb_ = (const char*)smem + 24576 + (R3) * 16384; \
    _Pragma("unroll") for (int m = 0; m < 4; ++m) af[m] = *(const bf16x8*)(ab_ + aofs[m]); \
    _Pragma("unroll") for (int j = 0; j < 4; ++j) bfr[j] = *(const bf16x8*)(bb_ + bofs[j]); \
  } while (0)
#define MFMA16() do { \
    __builtin_amdgcn_s_setprio(1); \
    _Pragma("unroll") for (int m = 0; m < 4; ++m) \
    _Pragma("unroll") for (int j = 0; j < 4; ++j) \
      acc[m][j] = __builtin_amdgcn_mfma_f32_16x16x32_bf16(af[m], bfr[j], acc[m][j], 0, 0, 0); \
    __builtin_amdgcn_s_setprio(0); } while (0)

  // prologue: stage tiles 0,1,2 (9 vm ops); vmcnt(6) -> own stage(0) complete
  STAGE(0, 0); STAGE(1, 1); STAGE(2, 2);
  asm volatile("s_waitcnt vmcnt(6)" ::: "memory");

  int r3 = 0;  // = t % 3
  for (int t = 0; t < 29; ++t) {
    __builtin_amdgcn_s_barrier();                      // stage(t) landed block-wide
    READS(r3);                                         // tile t fragments
    asm volatile("s_waitcnt lgkmcnt(0)" ::: "memory");
    __builtin_amdgcn_s_barrier();                      // all reads of buf[t%3] done
    STAGE(t + 3, r3);                                  // overwrite buf[t%3] with tile t+3
    MFMA16();                                          // tile t
    asm volatile("s_waitcnt vmcnt(6)" ::: "memory");   // own stage(t+1) complete
    r3 = (r3 == 2) ? 0 : r3 + 1;
  }
  // t=29 (r3=2): no stage; vmcnt(3) -> stage(30) done
  __builtin_amdgcn_s_barrier();
  READS(2);
  asm volatile("s_waitcnt lgkmcnt(0)" ::: "memory");
  __builtin_amdgcn_s_barrier();
  MFMA16();
  asm volatile("s_waitcnt vmcnt(3)" ::: "memory");
  // t=30 (buf 0): vmcnt(0) -> stage(31) done
  __builtin_amdgcn_s_barrier();
  READS(0);
  asm volatile("s_waitcnt lgkmcnt(0)" ::: "memory");
  __builtin_amdgcn_s_barrier();
  MFMA16();
  asm volatile("s_waitcnt vmcnt(0)" ::: "memory");
  // t=31 (buf 1)
  __builtin_amdgcn_s_barrier();
  READS(1);
  asm volatile("s_waitcnt lgkmcnt(0)" ::: "memory");
  MFMA16();

  // ---- epilogue ----
  const int wq = nb >> 2;                  // 0=q,1=k,2=v (block-uniform)
  const int h  = (nb & 3) * 4 + wc;        // head (wave-uniform)
  const int b  = mb >> 1;
  const int trow0 = (mb & 1) * 128 + wr * 64;
  if (wq < 2) {
    ushort_t* base = ((wq == 0) ? q_bf : k_bf) + (size_t)(b * 16 + h) * (SEQ * 64);
#pragma unroll
    for (int m = 0; m < 4; ++m)
#pragma unroll
      for (int j = 0; j < 4; ++j) {
        const int d = j * 16 + l15;
#pragma unroll
        for (int r = 0; r < 4; ++r)
          base[(size_t)(trow0 + m * 16 + quad * 4 + r) * 64 + d] = f2bf(acc[m][j][r]);
      }
  } else {
    __builtin_amdgcn_s_barrier();          // all waves past final reads -> smem reusable
    ushort_t* L = smem + wave * 4608;      // 64x72-pad transpose tile per wave (9216 B)
#pragma unroll
    for (int m = 0; m < 4; ++m)
#pragma unroll
      for (int j = 0; j < 4; ++j) {
        uint_t lo = (uint_t)f2bf(acc[m][j][0]) | ((uint_t)f2bf(acc[m][j][1]) << 16);
        uint_t hi = (uint_t)f2bf(acc[m][j][2]) | ((uint_t)f2bf(acc[m][j][3]) << 16);
        *(uint2*)&L[(j * 16 + l15) * 72 + m * 16 + quad * 4] = make_uint2(lo, hi);
      }
    ushort_t* vbase = vT_bf + (size_t)(b * 16 + h) * (64 * SEQ) + trow0;
    const int dr = lane >> 3, tc = (lane & 7) * 8;
#pragma unroll
    for (int u = 0; u < 8; ++u) {
      const int d = u * 8 + dr;
      uint4 val = *(const uint4*)&L[d * 72 + tc];
      *(uint4*)&vbase[(size_t)d * SEQ + tc] = val;
    }
  }
#undef STAGE
#undef READS
#undef MFMA16
}

// ---------------- stats: partial l[t,s], 16 bh per block via cross-wave LDS reduce ----
__global__ __launch_bounds__(256)
void stats_mfma(const ushort_t* __restrict__ qb, const ushort_t* __restrict__ kb,
                float* __restrict__ part_l) {
  const int p = blockIdx.x, g = blockIdx.y;   // g 0..63 -> one slot per block
  int tt, ss;
  if (p < 4) { tt = p; ss = p; }
  else {
    const int idx = p - 4;
    tt = (idx < 3) ? 0 : (idx < 5) ? 1 : 2;
    ss = (idx < 3) ? idx + 1 : (idx < 5) ? idx - 1 : 3;
  }
  const bool diag = (p < 4);
  const int tid = threadIdx.x, wave = tid >> 6, lane = tid & 63;
  const int l15 = lane & 15, quad = lane >> 4;

  __shared__ __attribute__((aligned(16))) float red[4][64 * 68];

  f32x4 lacc[4][4] = {};

  for (int i4 = 0; i4 < 4; ++i4) {
    const int bp = g * 16 + wave * 4 + i4;
    const int bh = (bp & 63) * 16 + (bp >> 6);
    const ushort_t* qt = qb + (size_t)bh * (SEQ * 64) + (size_t)(tt * 64) * 64;
    const ushort_t* kt = kb + (size_t)bh * (SEQ * 64) + (size_t)(ss * 64) * 64;
    bf16x8 aq[4][2], bk[4][2];
#pragma unroll
    for (int m = 0; m < 4; ++m)
#pragma unroll
      for (int ks = 0; ks < 2; ++ks) {
        aq[m][ks] = *(const bf16x8*)&qt[(m * 16 + l15) * 64 + ks * 32 + quad * 8];
        bk[m][ks] = *(const bf16x8*)&kt[(m * 16 + l15) * 64 + ks * 32 + quad * 8];
      }
    f32x4 sf[4][4] = {};
#pragma unroll
    for (int ks = 0; ks < 2; ++ks)
#pragma unroll
      for (int m = 0; m < 4; ++m)
#pragma unroll
        for (int n = 0; n < 4; ++n)
          sf[m][n] = __builtin_amdgcn_mfma_f32_16x16x32_bf16(aq[m][ks], bk[n][ks], sf[m][n], 0, 0, 0);
#pragma unroll
    for (int m = 0; m < 4; ++m)
#pragma unroll
      for (int n = 0; n < 4; ++n)
#pragma unroll
        for (int r = 0; r < 4; ++r) {
          float e = __expf(sf[m][n][r] * SCALE);
          if (diag) {
            const int t = tt * 64 + m * 16 + quad * 4 + r;
            const int s = ss * 64 + n * 16 + l15;
            e = (s > t) ? e : 1.0f;
          }
          lacc[m][n][r] += e;
        }
  }
  float* R = red[wave];
#pragma unroll
  for (int m = 0; m < 4; ++m)
#pragma unroll
    for (int r = 0; r < 4; ++r) {
      const int row = m * 16 + quad * 4 + r;
#pragma unroll
      for (int n = 0; n < 4; ++n)
        R[row * 68 + n * 16 + l15] = lacc[m][n][r];
    }
  __syncthreads();
  const int trow = tid >> 2, c0 = (tid & 3) * 16;
  const float* r0 = &red[0][trow * 68 + c0];
  const float* r1 = &red[1][trow * 68 + c0];
  const float* r2 = &red[2][trow * 68 + c0];
  const float* r3 = &red[3][trow * 68 + c0];
  float* pl = part_l + (size_t)g * (SEQ * SEQ) + (size_t)(tt * 64 + trow) * SEQ + ss * 64 + c0;
#pragma unroll
  for (int c = 0; c < 16; c += 4) {
    float4 s0 = *(const float4*)&r0[c];
    float4 s1 = *(const float4*)&r1[c];
    float4 s2 = *(const float4*)&r2[c];
    float4 s3 = *(const float4*)&r3[c];
    float4 o;
    o.x = (s0.x + s1.x) + (s2.x + s3.x);
    o.y = (s0.y + s1.y) + (s2.y + s3.y);
    o.z = (s0.z + s1.z) + (s2.z + s3.z);
    o.w = (s0.w + s1.w) + (s2.w + s3.w);
    *(float4*)&pl[c] = o;
  }
}

// ---------------- merge: sum 64 slots -> inv_lT[s][t]; 8 accumulators for MLP --------
__global__ __launch_bounds__(256)
void merge_kernel(const float* __restrict__ part_l, float* __restrict__ inv_lT) {
  const int i = blockIdx.x * 256 + threadIdx.x;  // t*256+s
  const int t = i >> 8, s = i & 255;
  float invv;
  if (s <= t) invv = 1.0f / 1024.0f;
  else {
    const float* p = part_l + i;
    float a0 = 0.f, a1 = 0.f, a2 = 0.f, a3 = 0.f,
          a4 = 0.f, a5 = 0.f, a6 = 0.f, a7 = 0.f;
    for (int g = 0; g < 64; g += 8) {
      const float* q = p + ((size_t)g << 16);
      a0 += q[0ull << 16]; a1 += q[1ull << 16]; a2 += q[2ull << 16]; a3 += q[3ull << 16];
      a4 += q[4ull << 16]; a5 += q[5ull << 16]; a6 += q[6ull << 16]; a7 += q[7ull << 16];
    }
    invv = 1.0f / (((a0 + a1) + (a2 + a3)) + ((a4 + a5) + (a6 + a7)));
  }
  inv_lT[s * SEQ + t] = invv;
}

// ---------------- pv: recompute S^T, P=e*inv (bf16, LDS), O = P.V via MFMA ----------------
__global__ __launch_bounds__(256)
void pv_mfma(const ushort_t* __restrict__ qb, const ushort_t* __restrict__ kb,
             const ushort_t* __restrict__ vtb, const float* __restrict__ inv_lT,
             float* __restrict__ out) {
  const int bh = blockIdx.x;
  const int b = bh >> 4, h = bh & 15;
  const int tid = threadIdx.x, wave = tid >> 6, lane = tid & 63;
  const int l15 = lane & 15, quad = lane >> 4;
  const int t0 = wave * 64;

  __shared__ ushort_t Plds[4][64][72];
  ushort_t (*Pw)[72] = Plds[wave];

  const ushort_t* qq = qb + (size_t)bh * (SEQ * 64);
  const ushort_t* kk = kb + (size_t)bh * (SEQ * 64);
  const ushort_t* vv = vtb + (size_t)bh * (64 * SEQ);

  bf16x8 qf[4][2];
#pragma unroll
  for (int nt = 0; nt < 4; ++nt)
#pragma unroll
    for (int ks = 0; ks < 2; ++ks)
      qf[nt][ks] = *(const bf16x8*)&qq[(t0 + nt * 16 + l15) * 64 + ks * 32 + quad * 8];

  f32x4 o[4][4] = {};

  for (int sc = 0; sc < 4; ++sc) {
    if (sc < wave) {
      const uint_t c = 0x3A803A80u;  // bf16 1/1024, exact
      const uint4 cc = make_uint4(c, c, c, c);
#pragma unroll
      for (int u = 0; u < 8; ++u) *(uint4*)&Pw[lane][u * 8] = cc;
    } else {
      bf16x8 kf[4][2];
#pragma unroll
      for (int ms = 0; ms < 4; ++ms)
#pragma unroll
        for (int ks = 0; ks < 2; ++ks)
          kf[ms][ks] = *(const bf16x8*)&kk[(sc * 64 + ms * 16 + l15) * 64 + ks * 32 + quad * 8];
      f32x4 sf[4][4] = {};
#pragma unroll
      for (int ks = 0; ks < 2; ++ks)
#pragma unroll
        for (int ms = 0; ms < 4; ++ms)
#pragma unroll
          for (int nt = 0; nt < 4; ++nt)
            sf[ms][nt] = __builtin_amdgcn_mfma_f32_16x16x32_bf16(kf[ms][ks], qf[nt][ks], sf[ms][nt], 0, 0, 0);
      const bool dg = (sc == wave);
      const int t = t0 + l15;
#pragma unroll
      for (int ms = 0; ms < 4; ++ms)
#pragma unroll
        for (int nt = 0; nt < 4; ++nt) {
          const int sb = sc * 64 + ms * 16 + quad * 4;
          const int tc = t + nt * 16;
          ushort_t pb[4];
#pragma unroll
          for (int r = 0; r < 4; ++r) {
            const int s = sb + r;
            float e = __expf(sf[ms][nt][r] * SCALE);
            if (dg) e = (s > tc) ? e : 1.0f;
            pb[r] = f2bf(e * inv_lT[(size_t)s * SEQ + tc]);
          }
          uint_t lo = (uint_t)pb[0] | ((uint_t)pb[1] << 16);
          uint_t hi = (uint_t)pb[2] | ((uint_t)pb[3] << 16);
          *(uint2*)&Pw[nt * 16 + l15][ms * 16 + quad * 4] = make_uint2(lo, hi);
        }
    }
    bf16x8 vf[4][2], pf[4][2];
#pragma unroll
    for (int nd = 0; nd < 4; ++nd)
#pragma unroll
      for (int ks = 0; ks < 2; ++ks)
        vf[nd][ks] = *(const bf16x8*)&vv[(nd * 16 + l15) * SEQ + sc * 64 + ks * 32 + quad * 8];
#pragma unroll
    for (int mt = 0; mt < 4; ++mt)
#pragma unroll
      for (int ks = 0; ks < 2; ++ks)
        pf[mt][ks] = *(const bf16x8*)&Pw[mt * 16 + l15][ks * 32 + quad * 8];
#pragma unroll
    for (int ks = 0; ks < 2; ++ks)
#pragma unroll
      for (int mt = 0; mt < 4; ++mt)
#pragma unroll
        for (int nd = 0; nd < 4; ++nd)
          o[mt][nd] = __builtin_amdgcn_mfma_f32_16x16x32_bf16(pf[mt][ks], vf[nd][ks], o[mt][nd], 0, 0, 0);
  }

  float* ob = out + (size_t)b * SEQ * DIM + h * 64;
#pragma unroll
  for (int mt = 0; mt < 4; ++mt)
#pragma unroll
    for (int r = 0; r < 4; ++r) {
      const int t = t0 + mt * 16 + quad * 4 + r;
#pragma unroll
      for (int nd = 0; nd < 4; ++nd)
        ob[(size_t)t * DIM + nd * 16 + l15] = o[mt][nd][r];
    }
}

extern "C" void kernel_launch(void* const* d_in, const int* in_sizes, int n_in,
                              void* d_out, int out_size, void* d_ws, size_t ws_size,
                              hipStream_t stream) {
  const float* x   = (const float*)d_in[0];
  const float* pos = (const float*)d_in[1];
  const float* Wq  = (const float*)d_in[2];
  const float* Wk  = (const float*)d_in[3];
  const float* Wv  = (const float*)d_in[4];
  float* out = (float*)d_out;

  // A_bf (33.5 MB) + Bp (6.3 MB) live in d_out (67 MB); both are dead before
  // pv_mfma fully overwrites d_out.
  ushort_t* Ab = (ushort_t*)d_out;
  ushort_t* Bp = (ushort_t*)((char*)d_out + 33554432);

  char* W = (char*)d_ws;
  ushort_t* q_bf   = (ushort_t*)(W);                  //  33,554,432 B  [b][h][t][d]
  ushort_t* k_bf   = (ushort_t*)(W + 33554432);       //  33,554,432 B
  ushort_t* vT_bf  = (ushort_t*)(W + 67108864);       //  33,554,432 B  [b][h][d][t]
  float*    part_l = (float*)  (W + 100663296);       //  16,777,216 B  (64 slots)
  float*    inv_lT = (float*)  (W + 167772160);       //     262,144 B

  prep_a<<<dim3(8192), 256, 0, stream>>>(x, pos, Ab);
  pack_w<<<dim3(4, 128, 3), 256, 0, stream>>>(Wq, Wk, Wv, Bp);
  qkv_mfma<<<dim3(12, 128), 512, 0, stream>>>(Ab, Bp, q_bf, k_bf, vT_bf);
  stats_mfma<<<dim3(10, 64), 256, 0, stream>>>(q_bf, k_bf, part_l);
  merge_kernel<<<dim3(SEQ * SEQ / 256), 256, 0, stream>>>(part_l, inv_lT);
  pv_mfma<<<dim3(1024), 256, 0, stream>>>(q_bf, k_bf, vT_bf, inv_lT, out);
}

// Round 5
// 339.850 us; speedup vs baseline: 1.0402x; 1.0402x over previous
//
#include <hip/hip_runtime.h>

constexpr int SEQ = 256;
constexpr int DIM = 1024;
constexpr float SCALE = 0.0625f;  // 1/sqrt(256)

typedef __attribute__((ext_vector_type(8))) short bf16x8;
typedef __attribute__((ext_vector_type(4))) float f32x4;
typedef unsigned short ushort_t;
typedef unsigned int uint_t;

__device__ __forceinline__ void gld_lds16(const void* g, void* l) {
  __builtin_amdgcn_global_load_lds(
      (const __attribute__((address_space(1))) unsigned int*)g,
      (__attribute__((address_space(3))) unsigned int*)l, 16, 0, 0);
}

__device__ __forceinline__ ushort_t f2bf(float f) {  // round-to-nearest-even
  uint_t u = __float_as_uint(f);
  return (ushort_t)((u + 0x7fffu + ((u >> 16) & 1u)) >> 16);
}

// ---------------- prep_a: A_bf[m][k] = bf16(x + pos), row-major [16384][1024] ----------
__global__ __launch_bounds__(256)
void prep_a(const float* __restrict__ x, const float* __restrict__ pos,
            ushort_t* __restrict__ Ab) {
  const size_t idx = ((size_t)blockIdx.x * 256 + threadIdx.x) * 8;
  const int m = (int)(idx >> 10), k = (int)(idx & 1023);
  float4 x0 = *(const float4*)(x + idx);
  float4 x1 = *(const float4*)(x + idx + 4);
  const float* pp = pos + ((size_t)(m & 255) << 10) + k;
  float4 p0 = *(const float4*)pp;
  float4 p1 = *(const float4*)(pp + 4);
  uint_t w0 = (uint_t)f2bf(x0.x + p0.x) | ((uint_t)f2bf(x0.y + p0.y) << 16);
  uint_t w1 = (uint_t)f2bf(x0.z + p0.z) | ((uint_t)f2bf(x0.w + p0.w) << 16);
  uint_t w2 = (uint_t)f2bf(x1.x + p1.x) | ((uint_t)f2bf(x1.y + p1.y) << 16);
  uint_t w3 = (uint_t)f2bf(x1.z + p1.z) | ((uint_t)f2bf(x1.w + p1.w) << 16);
  *(uint4*)&Ab[idx] = make_uint4(w0, w1, w2, w3);
}

// ---------------- pack_w: W[k][n] fp32 -> bf16 tiles [nb 12][kc 16][n 256][k 64] -------
__global__ __launch_bounds__(256)
void pack_w(const float* __restrict__ Wq, const float* __restrict__ Wk,
            const float* __restrict__ Wv, ushort_t* __restrict__ Bp) {
  const float* W = (blockIdx.z == 0) ? Wq : (blockIdx.z == 1) ? Wk : Wv;
  const int n  = blockIdx.x * 256 + threadIdx.x;
  const int k8 = blockIdx.y * 8;
  uint_t h[8];
#pragma unroll
  for (int i = 0; i < 8; ++i) h[i] = f2bf(W[(size_t)(k8 + i) * DIM + n]);
  uint_t hp[4];
#pragma unroll
  for (int j = 0; j < 4; ++j) hp[j] = h[2 * j] | (h[2 * j + 1] << 16);
  const int np = blockIdx.z * 1024 + n;
  const int nb = np >> 8, nl = np & 255;
  const int kc = k8 >> 6, kk = k8 & 63;
  size_t base = (((size_t)nb * 16 + kc) * 256 + nl) * 64 + kk;
  *(uint4*)&Bp[base] = make_uint4(hp[0], hp[1], hp[2], hp[3]);
}

// ---------------- qkv: 256x256 tile, BK=64, 8 waves, counted lgkm/vmcnt pipeline ------
// R2-proven 5-phase schedule + XCD-aware block remap: hardware round-robins linear
// block id over 8 XCDs; we assign xcd = id&7 a contiguous chunk of 8 mb-panels with nb
// fastest, so the 512 KB A-panel is fetched once into that XCD's L2 and reused by all
// 12 nb-blocks (was: 12 different XCDs each re-fetching it from L3 -> 4x over-fetch,
// staging stalled on L3 latency).
__global__ __launch_bounds__(512, 2)
void qkv_mfma(const ushort_t* __restrict__ Ab, const ushort_t* __restrict__ Bp,
              ushort_t* __restrict__ q_bf, ushort_t* __restrict__ k_bf,
              ushort_t* __restrict__ vT_bf) {
  const int id = (int)blockIdx.x;       // 0..767
  const int q8 = id >> 3;               // 0..95
  const int nb = q8 % 12;               // fastest within an XCD's chunk
  const int mb = (id & 7) * 8 + q8 / 12;  // xcd owns mb in [xcd*8, xcd*8+8)
  const int tid = (int)threadIdx.x;
  const int wave = tid >> 6, lane = tid & 63;
  const int wm = wave >> 2, wn = wave & 3;
  const int l15 = lane & 15, quad = lane >> 4;

  __shared__ ushort_t smem[65536];  // buf c: A @ c*32768, B @ c*32768+16384 (ushorts)

  // staging constants: thread -> row band r8, phys chunk lane&7, fetch logical chunk ^r8
  const int r8 = lane >> 3;
  const int lc8 = ((lane & 7) ^ r8) * 8;
  const size_t a_row = ((size_t)(mb * 256 + wave * 8 + r8)) << 10;
  const size_t b_row = ((size_t)((nb * 16) * 256 + wave * 8 + r8)) << 6;
  const int wb = wave * 512;

#define SA(q, tt, c) gld_lds16(Ab + a_row + ((size_t)(q) << 16) + (size_t)(tt) * 64 + lc8, \
                               smem + (c) * 32768 + (q) * 4096 + wb)
#define SB(q, tt, c) gld_lds16(Bp + b_row + (size_t)(tt) * 16384 + (q) * 4096 + lc8, \
                               smem + (c) * 32768 + 16384 + (q) * 4096 + wb)

  // fragment read offsets (ushort idx): row*64 + ((ks*4+quad)^(row&7))*8
  const int swz = l15 & 7;
  const int cko0 = (quad ^ swz) * 8;
  const int cko1 = ((4 + quad) ^ swz) * 8;
  const int arow0 = (wm * 128 + l15) * 64;
  const int brow0 = (wn * 64 + l15) * 64;

  f32x4 acc[8][4] = {};
  bf16x8 af[4][2], bf[4][2];

#define LDA_II(IH, ii) do { \
    const int ro = arow0 + ((IH) * 64 + (ii) * 16) * 64; \
    af[ii][0] = *(const bf16x8*)&Ac[ro + cko0]; \
    af[ii][1] = *(const bf16x8*)&Ac[ro + cko1]; } while (0)
#define LDB_J(J) do { const int ro = brow0 + (J) * 1024; \
    bf[J][0] = *(const bf16x8*)&Bc[ro + cko0]; \
    bf[J][1] = *(const bf16x8*)&Bc[ro + cko1]; } while (0)
#define MMQ(IH, II0, II1, J0) do { \
    _Pragma("unroll") for (int ks = 0; ks < 2; ++ks) \
    _Pragma("unroll") for (int ii = (II0); ii < (II1); ++ii) \
    _Pragma("unroll") for (int jj = 0; jj < 2; ++jj) \
      acc[(IH) * 4 + ii][(J0) + jj] = __builtin_amdgcn_mfma_f32_16x16x32_bf16( \
          af[ii][ks], bf[(J0) + jj][ks], acc[(IH) * 4 + ii][(J0) + jj], 0, 0, 0); \
    } while (0)

  // prologue: tile0 complete + tile1 {Bq0,Bq1,Aq0,Aq2}; vmcnt(6) leaves the invariant set
  SA(0, 0, 0); SA(2, 0, 0); SB(0, 0, 0); SB(1, 0, 0); SB(2, 0, 0); SB(3, 0, 0);
  SA(1, 0, 0); SA(3, 0, 0);
  SB(0, 1, 1); SB(1, 1, 1); SA(0, 1, 1); SA(2, 1, 1);
  asm volatile("s_waitcnt vmcnt(6)" ::: "memory");
  __builtin_amdgcn_s_barrier();

  for (int t = 0; t < 16; ++t) {
    const int cur = t & 1, nxt = cur ^ 1;
    const int tn  = (t < 15) ? t + 1 : 15;   // clamped re-stage is benign (reads done first)
    const int tn2 = (t < 14) ? t + 2 : 15;
    const ushort_t* Ac = &smem[cur * 32768];
    const ushort_t* Bc = Ac + 16384;
    // P0: issue a0 (8r) + b01 (4r) | stage Bq2,Bq3(t+1)
    LDA_II(0, 0); LDA_II(0, 1); LDA_II(0, 2); LDA_II(0, 3);
    LDB_J(0); LDB_J(1);
    SB(2, tn, nxt); SB(3, tn, nxt);
    __builtin_amdgcn_s_barrier();
    // P1: issue b23 ahead (flies under M00) | stage Aq1,Aq3(t+1) | M00 | vmcnt(8)
    LDB_J(2); LDB_J(3);
    SA(1, tn, nxt); SA(3, tn, nxt);
    asm volatile("s_waitcnt lgkmcnt(4)" ::: "memory");
    __builtin_amdgcn_s_setprio(1);
    MMQ(0, 0, 4, 0);
    __builtin_amdgcn_s_setprio(0);
    asm volatile("s_waitcnt vmcnt(8)" ::: "memory");
    __builtin_amdgcn_s_barrier();
    // P2: M02 split, a1 reload interleaved into the dead af[] halves
    asm volatile("s_waitcnt lgkmcnt(0)" ::: "memory");
    __builtin_amdgcn_s_setprio(1);
    MMQ(0, 0, 2, 2);
    __builtin_amdgcn_s_setprio(0);
    LDA_II(1, 0); LDA_II(1, 1);
    __builtin_amdgcn_s_setprio(1);
    MMQ(0, 2, 4, 2);
    __builtin_amdgcn_s_setprio(0);
    LDA_II(1, 2); LDA_II(1, 3);
    __builtin_amdgcn_s_barrier();
    // P3: stage Bq0,Bq1(t+2)->cur (all B reads retired) | M12
    SB(0, tn2, cur); SB(1, tn2, cur);
    asm volatile("s_waitcnt lgkmcnt(0)" ::: "memory");
    __builtin_amdgcn_s_setprio(1);
    MMQ(1, 0, 4, 2);
    __builtin_amdgcn_s_setprio(0);
    __builtin_amdgcn_s_barrier();
    // P4: stage Aq0,Aq2(t+2)->cur | M10 (regs only) | vmcnt(6)
    SA(0, tn2, cur); SA(2, tn2, cur);
    __builtin_amdgcn_s_setprio(1);
    MMQ(1, 0, 4, 0);
    __builtin_amdgcn_s_setprio(0);
    asm volatile("s_waitcnt vmcnt(6)" ::: "memory");
    __builtin_amdgcn_s_barrier();
  }

  // epilogue: drain our async LDS writes before reuse/exit
  asm volatile("s_waitcnt vmcnt(0)" ::: "memory");
  const int wq = nb >> 2;                 // 0=q,1=k,2=v (block-uniform)
  const int h  = (nb & 3) * 4 + wn;       // head (wave-uniform)
  if (wq < 2) {
    ushort_t* base = ((wq == 0) ? q_bf : k_bf) + (size_t)(mb * 16 + h) * (SEQ * 64);
    const int tb = wm * 128 + quad * 4;
#pragma unroll
    for (int i = 0; i < 8; ++i)
#pragma unroll
      for (int j = 0; j < 4; ++j) {
        const int d = j * 16 + l15;
#pragma unroll
        for (int r = 0; r < 4; ++r)
          base[(size_t)(tb + i * 16 + r) * 64 + d] = f2bf(acc[i][j][r]);
      }
  } else {
    __builtin_amdgcn_s_barrier();  // all waves drained -> safe to overwrite smem
    ushort_t* L = &smem[wave * 4608];   // 64x72-pad transpose tile per wave
    ushort_t* vbase = vT_bf + (size_t)(mb * 16 + h) * (64 * SEQ) + wm * 128;
    const int tc = (lane & 7) * 8;
#pragma unroll
    for (int g = 0; g < 2; ++g) {
#pragma unroll
      for (int ii = 0; ii < 4; ++ii)
#pragma unroll
        for (int j = 0; j < 4; ++j) {
          f32x4 v = acc[g * 4 + ii][j];
          uint_t lo = (uint_t)f2bf(v[0]) | ((uint_t)f2bf(v[1]) << 16);
          uint_t hi = (uint_t)f2bf(v[2]) | ((uint_t)f2bf(v[3]) << 16);
          *(uint2*)&L[(j * 16 + l15) * 72 + ii * 16 + quad * 4] = make_uint2(lo, hi);
        }
#pragma unroll
      for (int u = 0; u < 8; ++u) {
        const int d = u * 8 + r8;
        uint4 val = *(const uint4*)&L[d * 72 + tc];
        *(uint4*)&vbase[(size_t)d * SEQ + g * 64 + tc] = val;
      }
    }
  }
#undef SA
#undef SB
#undef LDA_II
#undef LDB_J
#undef MMQ
}

// ---------------- stats: partial l[t,s], 32 bh per block via cross-wave LDS reduce ----
__global__ __launch_bounds__(256)
void stats_mfma(const ushort_t* __restrict__ qb, const ushort_t* __restrict__ kb,
                float* __restrict__ part_l) {
  const int p = blockIdx.x, g = blockIdx.y;   // g 0..31 -> one slot per block
  int tt, ss;
  if (p < 4) { tt = p; ss = p; }
  else {
    const int idx = p - 4;
    tt = (idx < 3) ? 0 : (idx < 5) ? 1 : 2;
    ss = (idx < 3) ? idx + 1 : (idx < 5) ? idx - 1 : 3;
  }
  const bool diag = (p < 4);
  const int tid = threadIdx.x, wave = tid >> 6, lane = tid & 63;
  const int l15 = lane & 15, quad = lane >> 4;

  __shared__ __attribute__((aligned(16))) float red[4][64 * 68];

  f32x4 lacc[4][4] = {};

  for (int i4 = 0; i4 < 8; ++i4) {
    const int bp = g * 32 + wave * 8 + i4;
    const int bh = (bp & 63) * 16 + (bp >> 6);
    const ushort_t* qt = qb + (size_t)bh * (SEQ * 64) + (size_t)(tt * 64) * 64;
    const ushort_t* kt = kb + (size_t)bh * (SEQ * 64) + (size_t)(ss * 64) * 64;
    bf16x8 aq[4][2], bk[4][2];
#pragma unroll
    for (int m = 0; m < 4; ++m)
#pragma unroll
      for (int ks = 0; ks < 2; ++ks) {
        aq[m][ks] = *(const bf16x8*)&qt[(m * 16 + l15) * 64 + ks * 32 + quad * 8];
        bk[m][ks] = *(const bf16x8*)&kt[(m * 16 + l15) * 64 + ks * 32 + quad * 8];
      }
    f32x4 sf[4][4] = {};
#pragma unroll
    for (int ks = 0; ks < 2; ++ks)
#pragma unroll
      for (int m = 0; m < 4; ++m)
#pragma unroll
        for (int n = 0; n < 4; ++n)
          sf[m][n] = __builtin_amdgcn_mfma_f32_16x16x32_bf16(aq[m][ks], bk[n][ks], sf[m][n], 0, 0, 0);
#pragma unroll
    for (int m = 0; m < 4; ++m)
#pragma unroll
      for (int n = 0; n < 4; ++n)
#pragma unroll
        for (int r = 0; r < 4; ++r) {
          float e = __expf(sf[m][n][r] * SCALE);
          if (diag) {
            const int t = tt * 64 + m * 16 + quad * 4 + r;
            const int s = ss * 64 + n * 16 + l15;
            e = (s > t) ? e : 1.0f;
          }
          lacc[m][n][r] += e;
        }
  }
  float* R = red[wave];
#pragma unroll
  for (int m = 0; m < 4; ++m)
#pragma unroll
    for (int r = 0; r < 4; ++r) {
      const int row = m * 16 + quad * 4 + r;
#pragma unroll
      for (int n = 0; n < 4; ++n)
        R[row * 68 + n * 16 + l15] = lacc[m][n][r];
    }
  __syncthreads();
  const int trow = tid >> 2, c0 = (tid & 3) * 16;
  const float* r0 = &red[0][trow * 68 + c0];
  const float* r1 = &red[1][trow * 68 + c0];
  const float* r2 = &red[2][trow * 68 + c0];
  const float* r3 = &red[3][trow * 68 + c0];
  float* pl = part_l + (size_t)g * (SEQ * SEQ) + (size_t)(tt * 64 + trow) * SEQ + ss * 64 + c0;
#pragma unroll
  for (int c = 0; c < 16; c += 4) {
    float4 s0 = *(const float4*)&r0[c];
    float4 s1 = *(const float4*)&r1[c];
    float4 s2 = *(const float4*)&r2[c];
    float4 s3 = *(const float4*)&r3[c];
    float4 o;
    o.x = (s0.x + s1.x) + (s2.x + s3.x);
    o.y = (s0.y + s1.y) + (s2.y + s3.y);
    o.z = (s0.z + s1.z) + (s2.z + s3.z);
    o.w = (s0.w + s1.w) + (s2.w + s3.w);
    *(float4*)&pl[c] = o;
  }
}

// ---------------- merge: sum 32 slots -> inv_lT[s][t]; 8 accumulators for MLP --------
__global__ __launch_bounds__(256)
void merge_kernel(const float* __restrict__ part_l, float* __restrict__ inv_lT) {
  const int i = blockIdx.x * 256 + threadIdx.x;  // t*256+s
  const int t = i >> 8, s = i & 255;
  float invv;
  if (s <= t) invv = 1.0f / 1024.0f;
  else {
    const float* p = part_l + i;
    float a0 = 0.f, a1 = 0.f, a2 = 0.f, a3 = 0.f,
          a4 = 0.f, a5 = 0.f, a6 = 0.f, a7 = 0.f;
    for (int g = 0; g < 32; g += 8) {
      const float* q = p + ((size_t)g << 16);
      a0 += q[0ull << 16]; a1 += q[1ull << 16]; a2 += q[2ull << 16]; a3 += q[3ull << 16];
      a4 += q[4ull << 16]; a5 += q[5ull << 16]; a6 += q[6ull << 16]; a7 += q[7ull << 16];
    }
    invv = 1.0f / (((a0 + a1) + (a2 + a3)) + ((a4 + a5) + (a6 + a7)));
  }
  inv_lT[s * SEQ + t] = invv;
}

// ---------------- pv: recompute S^T, P=e*inv (bf16, LDS), O = P.V via MFMA ----------------
__global__ __launch_bounds__(256)
void pv_mfma(const ushort_t* __restrict__ qb, const ushort_t* __restrict__ kb,
             const ushort_t* __restrict__ vtb, const float* __restrict__ inv_lT,
             float* __restrict__ out) {
  const int bh = blockIdx.x;
  const int b = bh >> 4, h = bh & 15;
  const int tid = threadIdx.x, wave = tid >> 6, lane = tid & 63;
  const int l15 = lane & 15, quad = lane >> 4;
  const int t0 = wave * 64;

  __shared__ ushort_t Plds[4][64][72];
  ushort_t (*Pw)[72] = Plds[wave];

  const ushort_t* qq = qb + (size_t)bh * (SEQ * 64);
  const ushort_t* kk = kb + (size_t)bh * (SEQ * 64);
  const ushort_t* vv = vtb + (size_t)bh * (64 * SEQ);

  bf16x8 qf[4][2];
#pragma unroll
  for (int nt = 0; nt < 4; ++nt)
#pragma unroll
    for (int ks = 0; ks < 2; ++ks)
      qf[nt][ks] = *(const bf16x8*)&qq[(t0 + nt * 16 + l15) * 64 + ks * 32 + quad * 8];

  f32x4 o[4][4] = {};

  for (int sc = 0; sc < 4; ++sc) {
    if (sc < wave) {
      const uint_t c = 0x3A803A80u;  // bf16 1/1024, exact
      const uint4 cc = make_uint4(c, c, c, c);
#pragma unroll
      for (int u = 0; u < 8; ++u) *(uint4*)&Pw[lane][u * 8] = cc;
    } else {
      bf16x8 kf[4][2];
#pragma unroll
      for (int ms = 0; ms < 4; ++ms)
#pragma unroll
        for (int ks = 0; ks < 2; ++ks)
          kf[ms][ks] = *(const bf16x8*)&kk[(sc * 64 + ms * 16 + l15) * 64 + ks * 32 + quad * 8];
      f32x4 sf[4][4] = {};
#pragma unroll
      for (int ks = 0; ks < 2; ++ks)
#pragma unroll
        for (int ms = 0; ms < 4; ++ms)
#pragma unroll
          for (int nt = 0; nt < 4; ++nt)
            sf[ms][nt] = __builtin_amdgcn_mfma_f32_16x16x32_bf16(kf[ms][ks], qf[nt][ks], sf[ms][nt], 0, 0, 0);
      const bool dg = (sc == wave);
      const int t = t0 + l15;
#pragma unroll
      for (int ms = 0; ms < 4; ++ms)
#pragma unroll
        for (int nt = 0; nt < 4; ++nt) {
          const int sb = sc * 64 + ms * 16 + quad * 4;
          const int tc = t + nt * 16;
          ushort_t pb[4];
#pragma unroll
          for (int r = 0; r < 4; ++r) {
            const int s = sb + r;
            float e = __expf(sf[ms][nt][r] * SCALE);
            if (dg) e = (s > tc) ? e : 1.0f;
            pb[r] = f2bf(e * inv_lT[(size_t)s * SEQ + tc]);
          }
          uint_t lo = (uint_t)pb[0] | ((uint_t)pb[1] << 16);
          uint_t hi = (uint_t)pb[2] | ((uint_t)pb[3] << 16);
          *(uint2*)&Pw[nt * 16 + l15][ms * 16 + quad * 4] = make_uint2(lo, hi);
        }
    }
    bf16x8 vf[4][2], pf[4][2];
#pragma unroll
    for (int nd = 0; nd < 4; ++nd)
#pragma unroll
      for (int ks = 0; ks < 2; ++ks)
        vf[nd][ks] = *(const bf16x8*)&vv[(nd * 16 + l15) * SEQ + sc * 64 + ks * 32 + quad * 8];
#pragma unroll
    for (int mt = 0; mt < 4; ++mt)
#pragma unroll
      for (int ks = 0; ks < 2; ++ks)
        pf[mt][ks] = *(const bf16x8*)&Pw[mt * 16 + l15][ks * 32 + quad * 8];
#pragma unroll
    for (int ks = 0; ks < 2; ++ks)
#pragma unroll
      for (int mt = 0; mt < 4; ++mt)
#pragma unroll
        for (int nd = 0; nd < 4; ++nd)
          o[mt][nd] = __builtin_amdgcn_mfma_f32_16x16x32_bf16(pf[mt][ks], vf[nd][ks], o[mt][nd], 0, 0, 0);
  }

  float* ob = out + (size_t)b * SEQ * DIM + h * 64;
#pragma unroll
  for (int mt = 0; mt < 4; ++mt)
#pragma unroll
    for (int r = 0; r < 4; ++r) {
      const int t = t0 + mt * 16 + quad * 4 + r;
#pragma unroll
      for (int nd = 0; nd < 4; ++nd)
        ob[(size_t)t * DIM + nd * 16 + l15] = o[mt][nd][r];
    }
}

extern "C" void kernel_launch(void* const* d_in, const int* in_sizes, int n_in,
                              void* d_out, int out_size, void* d_ws, size_t ws_size,
                              hipStream_t stream) {
  const float* x   = (const float*)d_in[0];
  const float* pos = (const float*)d_in[1];
  const float* Wq  = (const float*)d_in[2];
  const float* Wk  = (const float*)d_in[3];
  const float* Wv  = (const float*)d_in[4];
  float* out = (float*)d_out;

  // A_bf (33.5 MB) + Bp (6.3 MB) live in d_out (67 MB); both are dead before
  // pv_mfma fully overwrites d_out.
  ushort_t* Ab = (ushort_t*)d_out;
  ushort_t* Bp = (ushort_t*)((char*)d_out + 33554432);

  char* W = (char*)d_ws;
  ushort_t* q_bf   = (ushort_t*)(W);                  //  33,554,432 B  [b][h][t][d]
  ushort_t* k_bf   = (ushort_t*)(W + 33554432);       //  33,554,432 B
  ushort_t* vT_bf  = (ushort_t*)(W + 67108864);       //  33,554,432 B  [b][h][d][t]
  float*    part_l = (float*)  (W + 100663296);       //   8,388,608 B  (32 slots)
  float*    inv_lT = (float*)  (W + 167772160);       //     262,144 B

  prep_a<<<dim3(8192), 256, 0, stream>>>(x, pos, Ab);
  pack_w<<<dim3(4, 128, 3), 256, 0, stream>>>(Wq, Wk, Wv, Bp);
  qkv_mfma<<<dim3(768), 512, 0, stream>>>(Ab, Bp, q_bf, k_bf, vT_bf);
  stats_mfma<<<dim3(10, 32), 256, 0, stream>>>(q_bf, k_bf, part_l);
  merge_kernel<<<dim3(SEQ * SEQ / 256), 256, 0, stream>>>(part_l, inv_lT);
  pv_mfma<<<dim3(1024), 256, 0, stream>>>(q_bf, k_bf, vT_bf, inv_lT, out);
}

// Round 6
// 323.816 us; speedup vs baseline: 1.0917x; 1.0495x over previous
//
#include <hip/hip_runtime.h>

constexpr int SEQ = 256;
constexpr int DIM = 1024;
constexpr float SCALE = 0.0625f;  // 1/sqrt(256)

typedef __attribute__((ext_vector_type(8))) short bf16x8;
typedef __attribute__((ext_vector_type(4))) float f32x4;
typedef unsigned short ushort_t;
typedef unsigned int uint_t;

__device__ __forceinline__ void gld_lds16(const void* g, void* l) {
  __builtin_amdgcn_global_load_lds(
      (const __attribute__((address_space(1))) unsigned int*)g,
      (__attribute__((address_space(3))) unsigned int*)l, 16, 0, 0);
}

__device__ __forceinline__ ushort_t f2bf(float f) {  // round-to-nearest-even
  uint_t u = __float_as_uint(f);
  return (ushort_t)((u + 0x7fffu + ((u >> 16) & 1u)) >> 16);
}

__device__ __forceinline__ float bf2f(ushort_t h) {
  return __uint_as_float(((uint_t)h) << 16);
}

// ---------------- prep_pack: fused prep_a (blocks 0..8191) + pack_w (8192..9727) ------
// prep: A_bf[m][k] = bf16(x + pos), row-major [16384][1024]
// pack: W[k][n] fp32 -> bf16 tiles [nb 12][kc 16][n 256][k 64]
__global__ __launch_bounds__(256)
void prep_pack(const float* __restrict__ x, const float* __restrict__ pos,
               const float* __restrict__ Wq, const float* __restrict__ Wk,
               const float* __restrict__ Wv,
               ushort_t* __restrict__ Ab, ushort_t* __restrict__ Bp) {
  const int bid = (int)blockIdx.x;
  if (bid < 8192) {
    const size_t idx = ((size_t)bid * 256 + threadIdx.x) * 8;
    const int m = (int)(idx >> 10), k = (int)(idx & 1023);
    float4 x0 = *(const float4*)(x + idx);
    float4 x1 = *(const float4*)(x + idx + 4);
    const float* pp = pos + ((size_t)(m & 255) << 10) + k;
    float4 p0 = *(const float4*)pp;
    float4 p1 = *(const float4*)(pp + 4);
    uint_t w0 = (uint_t)f2bf(x0.x + p0.x) | ((uint_t)f2bf(x0.y + p0.y) << 16);
    uint_t w1 = (uint_t)f2bf(x0.z + p0.z) | ((uint_t)f2bf(x0.w + p0.w) << 16);
    uint_t w2 = (uint_t)f2bf(x1.x + p1.x) | ((uint_t)f2bf(x1.y + p1.y) << 16);
    uint_t w3 = (uint_t)f2bf(x1.z + p1.z) | ((uint_t)f2bf(x1.w + p1.w) << 16);
    *(uint4*)&Ab[idx] = make_uint4(w0, w1, w2, w3);
  } else {
    const int pid = bid - 8192;                 // 0..1535
    const int z = pid >> 9;                     // 0..2
    const int rem = pid & 511;
    const int by = rem >> 2, bx = rem & 3;
    const float* W = (z == 0) ? Wq : (z == 1) ? Wk : Wv;
    const int n  = bx * 256 + threadIdx.x;
    const int k8 = by * 8;
    uint_t h[8];
#pragma unroll
    for (int i = 0; i < 8; ++i) h[i] = f2bf(W[(size_t)(k8 + i) * DIM + n]);
    uint_t hp[4];
#pragma unroll
    for (int j = 0; j < 4; ++j) hp[j] = h[2 * j] | (h[2 * j + 1] << 16);
    const int np = z * 1024 + n;
    const int nb = np >> 8, nl = np & 255;
    const int kc = k8 >> 6, kk = k8 & 63;
    size_t base = (((size_t)nb * 16 + kc) * 256 + nl) * 64 + kk;
    *(uint4*)&Bp[base] = make_uint4(hp[0], hp[1], hp[2], hp[3]);
  }
}

// ---------------- qkv: 256x256 tile, BK=64, 8 waves, counted lgkm/vmcnt pipeline ------
// R5-proven: 5-phase counted schedule + XCD-aware block remap (FETCH 143->95 MB).
__global__ __launch_bounds__(512, 2)
void qkv_mfma(const ushort_t* __restrict__ Ab, const ushort_t* __restrict__ Bp,
              ushort_t* __restrict__ q_bf, ushort_t* __restrict__ k_bf,
              ushort_t* __restrict__ vT_bf) {
  const int id = (int)blockIdx.x;       // 0..767
  const int q8 = id >> 3;               // 0..95
  const int nb = q8 % 12;               // fastest within an XCD's chunk
  const int mb = (id & 7) * 8 + q8 / 12;  // xcd owns mb in [xcd*8, xcd*8+8)
  const int tid = (int)threadIdx.x;
  const int wave = tid >> 6, lane = tid & 63;
  const int wm = wave >> 2, wn = wave & 3;
  const int l15 = lane & 15, quad = lane >> 4;

  __shared__ ushort_t smem[65536];  // buf c: A @ c*32768, B @ c*32768+16384 (ushorts)

  const int r8 = lane >> 3;
  const int lc8 = ((lane & 7) ^ r8) * 8;
  const size_t a_row = ((size_t)(mb * 256 + wave * 8 + r8)) << 10;
  const size_t b_row = ((size_t)((nb * 16) * 256 + wave * 8 + r8)) << 6;
  const int wb = wave * 512;

#define SA(q, tt, c) gld_lds16(Ab + a_row + ((size_t)(q) << 16) + (size_t)(tt) * 64 + lc8, \
                               smem + (c) * 32768 + (q) * 4096 + wb)
#define SB(q, tt, c) gld_lds16(Bp + b_row + (size_t)(tt) * 16384 + (q) * 4096 + lc8, \
                               smem + (c) * 32768 + 16384 + (q) * 4096 + wb)

  const int swz = l15 & 7;
  const int cko0 = (quad ^ swz) * 8;
  const int cko1 = ((4 + quad) ^ swz) * 8;
  const int arow0 = (wm * 128 + l15) * 64;
  const int brow0 = (wn * 64 + l15) * 64;

  f32x4 acc[8][4] = {};
  bf16x8 af[4][2], bf[4][2];

#define LDA_II(IH, ii) do { \
    const int ro = arow0 + ((IH) * 64 + (ii) * 16) * 64; \
    af[ii][0] = *(const bf16x8*)&Ac[ro + cko0]; \
    af[ii][1] = *(const bf16x8*)&Ac[ro + cko1]; } while (0)
#define LDB_J(J) do { const int ro = brow0 + (J) * 1024; \
    bf[J][0] = *(const bf16x8*)&Bc[ro + cko0]; \
    bf[J][1] = *(const bf16x8*)&Bc[ro + cko1]; } while (0)
#define MMQ(IH, II0, II1, J0) do { \
    _Pragma("unroll") for (int ks = 0; ks < 2; ++ks) \
    _Pragma("unroll") for (int ii = (II0); ii < (II1); ++ii) \
    _Pragma("unroll") for (int jj = 0; jj < 2; ++jj) \
      acc[(IH) * 4 + ii][(J0) + jj] = __builtin_amdgcn_mfma_f32_16x16x32_bf16( \
          af[ii][ks], bf[(J0) + jj][ks], acc[(IH) * 4 + ii][(J0) + jj], 0, 0, 0); \
    } while (0)

  SA(0, 0, 0); SA(2, 0, 0); SB(0, 0, 0); SB(1, 0, 0); SB(2, 0, 0); SB(3, 0, 0);
  SA(1, 0, 0); SA(3, 0, 0);
  SB(0, 1, 1); SB(1, 1, 1); SA(0, 1, 1); SA(2, 1, 1);
  asm volatile("s_waitcnt vmcnt(6)" ::: "memory");
  __builtin_amdgcn_s_barrier();

  for (int t = 0; t < 16; ++t) {
    const int cur = t & 1, nxt = cur ^ 1;
    const int tn  = (t < 15) ? t + 1 : 15;
    const int tn2 = (t < 14) ? t + 2 : 15;
    const ushort_t* Ac = &smem[cur * 32768];
    const ushort_t* Bc = Ac + 16384;
    // P0
    LDA_II(0, 0); LDA_II(0, 1); LDA_II(0, 2); LDA_II(0, 3);
    LDB_J(0); LDB_J(1);
    SB(2, tn, nxt); SB(3, tn, nxt);
    __builtin_amdgcn_s_barrier();
    // P1
    LDB_J(2); LDB_J(3);
    SA(1, tn, nxt); SA(3, tn, nxt);
    asm volatile("s_waitcnt lgkmcnt(4)" ::: "memory");
    __builtin_amdgcn_s_setprio(1);
    MMQ(0, 0, 4, 0);
    __builtin_amdgcn_s_setprio(0);
    asm volatile("s_waitcnt vmcnt(8)" ::: "memory");
    __builtin_amdgcn_s_barrier();
    // P2
    asm volatile("s_waitcnt lgkmcnt(0)" ::: "memory");
    __builtin_amdgcn_s_setprio(1);
    MMQ(0, 0, 2, 2);
    __builtin_amdgcn_s_setprio(0);
    LDA_II(1, 0); LDA_II(1, 1);
    __builtin_amdgcn_s_setprio(1);
    MMQ(0, 2, 4, 2);
    __builtin_amdgcn_s_setprio(0);
    LDA_II(1, 2); LDA_II(1, 3);
    __builtin_amdgcn_s_barrier();
    // P3
    SB(0, tn2, cur); SB(1, tn2, cur);
    asm volatile("s_waitcnt lgkmcnt(0)" ::: "memory");
    __builtin_amdgcn_s_setprio(1);
    MMQ(1, 0, 4, 2);
    __builtin_amdgcn_s_setprio(0);
    __builtin_amdgcn_s_barrier();
    // P4
    SA(0, tn2, cur); SA(2, tn2, cur);
    __builtin_amdgcn_s_setprio(1);
    MMQ(1, 0, 4, 0);
    __builtin_amdgcn_s_setprio(0);
    asm volatile("s_waitcnt vmcnt(6)" ::: "memory");
    __builtin_amdgcn_s_barrier();
  }

  asm volatile("s_waitcnt vmcnt(0)" ::: "memory");
  const int wq = nb >> 2;
  const int h  = (nb & 3) * 4 + wn;
  if (wq < 2) {
    ushort_t* base = ((wq == 0) ? q_bf : k_bf) + (size_t)(mb * 16 + h) * (SEQ * 64);
    const int tb = wm * 128 + quad * 4;
#pragma unroll
    for (int i = 0; i < 8; ++i)
#pragma unroll
      for (int j = 0; j < 4; ++j) {
        const int d = j * 16 + l15;
#pragma unroll
        for (int r = 0; r < 4; ++r)
          base[(size_t)(tb + i * 16 + r) * 64 + d] = f2bf(acc[i][j][r]);
      }
  } else {
    __builtin_amdgcn_s_barrier();
    ushort_t* L = &smem[wave * 4608];
    ushort_t* vbase = vT_bf + (size_t)(mb * 16 + h) * (64 * SEQ) + wm * 128;
    const int tc = (lane & 7) * 8;
#pragma unroll
    for (int g = 0; g < 2; ++g) {
#pragma unroll
      for (int ii = 0; ii < 4; ++ii)
#pragma unroll
        for (int j = 0; j < 4; ++j) {
          f32x4 v = acc[g * 4 + ii][j];
          uint_t lo = (uint_t)f2bf(v[0]) | ((uint_t)f2bf(v[1]) << 16);
          uint_t hi = (uint_t)f2bf(v[2]) | ((uint_t)f2bf(v[3]) << 16);
          *(uint2*)&L[(j * 16 + l15) * 72 + ii * 16 + quad * 4] = make_uint2(lo, hi);
        }
#pragma unroll
      for (int u = 0; u < 8; ++u) {
        const int d = u * 8 + r8;
        uint4 val = *(const uint4*)&L[d * 72 + tc];
        *(uint4*)&vbase[(size_t)d * SEQ + g * 64 + tc] = val;
      }
    }
  }
#undef SA
#undef SB
#undef LDA_II
#undef LDB_J
#undef MMQ
}

// ---------------- stats: partial l[t,s], 32 bh per block via cross-wave LDS reduce ----
__global__ __launch_bounds__(256)
void stats_mfma(const ushort_t* __restrict__ qb, const ushort_t* __restrict__ kb,
                float* __restrict__ part_l) {
  const int p = blockIdx.x, g = blockIdx.y;
  int tt, ss;
  if (p < 4) { tt = p; ss = p; }
  else {
    const int idx = p - 4;
    tt = (idx < 3) ? 0 : (idx < 5) ? 1 : 2;
    ss = (idx < 3) ? idx + 1 : (idx < 5) ? idx - 1 : 3;
  }
  const bool diag = (p < 4);
  const int tid = threadIdx.x, wave = tid >> 6, lane = tid & 63;
  const int l15 = lane & 15, quad = lane >> 4;

  __shared__ __attribute__((aligned(16))) float red[4][64 * 68];

  f32x4 lacc[4][4] = {};

  for (int i4 = 0; i4 < 8; ++i4) {
    const int bp = g * 32 + wave * 8 + i4;
    const int bh = (bp & 63) * 16 + (bp >> 6);
    const ushort_t* qt = qb + (size_t)bh * (SEQ * 64) + (size_t)(tt * 64) * 64;
    const ushort_t* kt = kb + (size_t)bh * (SEQ * 64) + (size_t)(ss * 64) * 64;
    bf16x8 aq[4][2], bk[4][2];
#pragma unroll
    for (int m = 0; m < 4; ++m)
#pragma unroll
      for (int ks = 0; ks < 2; ++ks) {
        aq[m][ks] = *(const bf16x8*)&qt[(m * 16 + l15) * 64 + ks * 32 + quad * 8];
        bk[m][ks] = *(const bf16x8*)&kt[(m * 16 + l15) * 64 + ks * 32 + quad * 8];
      }
    f32x4 sf[4][4] = {};
#pragma unroll
    for (int ks = 0; ks < 2; ++ks)
#pragma unroll
      for (int m = 0; m < 4; ++m)
#pragma unroll
        for (int n = 0; n < 4; ++n)
          sf[m][n] = __builtin_amdgcn_mfma_f32_16x16x32_bf16(aq[m][ks], bk[n][ks], sf[m][n], 0, 0, 0);
#pragma unroll
    for (int m = 0; m < 4; ++m)
#pragma unroll
      for (int n = 0; n < 4; ++n)
#pragma unroll
        for (int r = 0; r < 4; ++r) {
          float e = __expf(sf[m][n][r] * SCALE);
          if (diag) {
            const int t = tt * 64 + m * 16 + quad * 4 + r;
            const int s = ss * 64 + n * 16 + l15;
            e = (s > t) ? e : 1.0f;
          }
          lacc[m][n][r] += e;
        }
  }
  float* R = red[wave];
#pragma unroll
  for (int m = 0; m < 4; ++m)
#pragma unroll
    for (int r = 0; r < 4; ++r) {
      const int row = m * 16 + quad * 4 + r;
#pragma unroll
      for (int n = 0; n < 4; ++n)
        R[row * 68 + n * 16 + l15] = lacc[m][n][r];
    }
  __syncthreads();
  const int trow = tid >> 2, c0 = (tid & 3) * 16;
  const float* r0 = &red[0][trow * 68 + c0];
  const float* r1 = &red[1][trow * 68 + c0];
  const float* r2 = &red[2][trow * 68 + c0];
  const float* r3 = &red[3][trow * 68 + c0];
  float* pl = part_l + (size_t)g * (SEQ * SEQ) + (size_t)(tt * 64 + trow) * SEQ + ss * 64 + c0;
#pragma unroll
  for (int c = 0; c < 16; c += 4) {
    float4 s0 = *(const float4*)&r0[c];
    float4 s1 = *(const float4*)&r1[c];
    float4 s2 = *(const float4*)&r2[c];
    float4 s3 = *(const float4*)&r3[c];
    float4 o;
    o.x = (s0.x + s1.x) + (s2.x + s3.x);
    o.y = (s0.y + s1.y) + (s2.y + s3.y);
    o.z = (s0.z + s1.z) + (s2.z + s3.z);
    o.w = (s0.w + s1.w) + (s2.w + s3.w);
    *(float4*)&pl[c] = o;
  }
}

// ---------------- merge: sum 32 slots -> inv_lT[s][t]; 8 accumulators for MLP --------
__global__ __launch_bounds__(256)
void merge_kernel(const float* __restrict__ part_l, float* __restrict__ inv_lT) {
  const int i = blockIdx.x * 256 + threadIdx.x;  // t*256+s
  const int t = i >> 8, s = i & 255;
  float invv;
  if (s <= t) invv = 1.0f / 1024.0f;
  else {
    const float* p = part_l + i;
    float a0 = 0.f, a1 = 0.f, a2 = 0.f, a3 = 0.f,
          a4 = 0.f, a5 = 0.f, a6 = 0.f, a7 = 0.f;
    for (int g = 0; g < 32; g += 8) {
      const float* q = p + ((size_t)g << 16);
      a0 += q[0ull << 16]; a1 += q[1ull << 16]; a2 += q[2ull << 16]; a3 += q[3ull << 16];
      a4 += q[4ull << 16]; a5 += q[5ull << 16]; a6 += q[6ull << 16]; a7 += q[7ull << 16];
    }
    invv = 1.0f / (((a0 + a1) + (a2 + a3)) + ((a4 + a5) + (a6 + a7)));
  }
  inv_lT[s * SEQ + t] = invv;
}

// ---------------- pv: recompute S^T (sc>=wave only), P=e*inv; constant-P prefix via colsum --
// Wave w's sc<w tiles have P == 1/1024 (exact power of 2): their contribution is
// (1/1024)*colsum(V-tile), computed once per block cooperatively (reads vT once, 1 KB LDS).
// Removes 6 of 16 (wave,sc) full iterations (vf loads, const-P fills, pf reads, 32 MFMA each).
__global__ __launch_bounds__(256)
void pv_mfma(const ushort_t* __restrict__ qb, const ushort_t* __restrict__ kb,
             const ushort_t* __restrict__ vtb, const float* __restrict__ inv_lT,
             float* __restrict__ out) {
  const int bh = blockIdx.x;
  const int b = bh >> 4, h = bh & 15;
  const int tid = threadIdx.x, wave = tid >> 6, lane = tid & 63;
  const int l15 = lane & 15, quad = lane >> 4;
  const int t0 = wave * 64;

  __shared__ ushort_t Plds[4][64][72];
  __shared__ float csumL[4][64];     // csumL[tile][d] = sum_{s in tile} vT[d][s]
  ushort_t (*Pw)[72] = Plds[wave];

  const ushort_t* qq = qb + (size_t)bh * (SEQ * 64);
  const ushort_t* kk = kb + (size_t)bh * (SEQ * 64);
  const ushort_t* vv = vtb + (size_t)bh * (64 * SEQ);

  // cooperative V column-sums: thread (tile=wave, d=lane) sums its 64-s stripe
  {
    const int d = lane;
    const ushort_t* vr = vv + (size_t)d * SEQ + wave * 64;
    float s = 0.f;
#pragma unroll
    for (int j = 0; j < 8; ++j) {
      bf16x8 v8 = *(const bf16x8*)&vr[j * 8];
#pragma unroll
      for (int e = 0; e < 8; ++e) s += bf2f((ushort_t)v8[e]);
    }
    csumL[wave][d] = s;
  }

  bf16x8 qf[4][2];
#pragma unroll
  for (int nt = 0; nt < 4; ++nt)
#pragma unroll
    for (int ks = 0; ks < 2; ++ks)
      qf[nt][ks] = *(const bf16x8*)&qq[(t0 + nt * 16 + l15) * 64 + ks * 32 + quad * 8];

  __syncthreads();   // csumL complete; no further cross-wave LDS sharing

  f32x4 o[4][4] = {};

  for (int sc = wave; sc < 4; ++sc) {
    bf16x8 kf[4][2];
#pragma unroll
    for (int ms = 0; ms < 4; ++ms)
#pragma unroll
      for (int ks = 0; ks < 2; ++ks)
        kf[ms][ks] = *(const bf16x8*)&kk[(sc * 64 + ms * 16 + l15) * 64 + ks * 32 + quad * 8];
    f32x4 sf[4][4] = {};
#pragma unroll
    for (int ks = 0; ks < 2; ++ks)
#pragma unroll
      for (int ms = 0; ms < 4; ++ms)
#pragma unroll
        for (int nt = 0; nt < 4; ++nt)
          sf[ms][nt] = __builtin_amdgcn_mfma_f32_16x16x32_bf16(kf[ms][ks], qf[nt][ks], sf[ms][nt], 0, 0, 0);
    const bool dg = (sc == wave);
    const int t = t0 + l15;
#pragma unroll
    for (int ms = 0; ms < 4; ++ms)
#pragma unroll
      for (int nt = 0; nt < 4; ++nt) {
        const int sb = sc * 64 + ms * 16 + quad * 4;
        const int tc = t + nt * 16;
        ushort_t pb[4];
#pragma unroll
        for (int r = 0; r < 4; ++r) {
          const int s = sb + r;
          float e = __expf(sf[ms][nt][r] * SCALE);
          if (dg) e = (s > tc) ? e : 1.0f;
          pb[r] = f2bf(e * inv_lT[(size_t)s * SEQ + tc]);
        }
        uint_t lo = (uint_t)pb[0] | ((uint_t)pb[1] << 16);
        uint_t hi = (uint_t)pb[2] | ((uint_t)pb[3] << 16);
        *(uint2*)&Pw[nt * 16 + l15][ms * 16 + quad * 4] = make_uint2(lo, hi);
      }

    bf16x8 vf[4][2], pf[4][2];
#pragma unroll
    for (int nd = 0; nd < 4; ++nd)
#pragma unroll
      for (int ks = 0; ks < 2; ++ks)
        vf[nd][ks] = *(const bf16x8*)&vv[(nd * 16 + l15) * SEQ + sc * 64 + ks * 32 + quad * 8];
#pragma unroll
    for (int mt = 0; mt < 4; ++mt)
#pragma unroll
      for (int ks = 0; ks < 2; ++ks)
        pf[mt][ks] = *(const bf16x8*)&Pw[mt * 16 + l15][ks * 32 + quad * 8];
#pragma unroll
    for (int ks = 0; ks < 2; ++ks)
#pragma unroll
      for (int mt = 0; mt < 4; ++mt)
#pragma unroll
        for (int nd = 0; nd < 4; ++nd)
          o[mt][nd] = __builtin_amdgcn_mfma_f32_16x16x32_bf16(pf[mt][ks], vf[nd][ks], o[mt][nd], 0, 0, 0);
  }

  // constant-P prefix: O[t,d] += (1/1024) * sum_{s < wave*64} vT[d][s]  (t-independent)
#pragma unroll
  for (int nd = 0; nd < 4; ++nd) {
    const int d = nd * 16 + l15;
    float pref = 0.f;
    for (int w2 = 0; w2 < wave; ++w2) pref += csumL[w2][d];
    const float cc = pref * (1.0f / 1024.0f);
#pragma unroll
    for (int mt = 0; mt < 4; ++mt)
#pragma unroll
      for (int r = 0; r < 4; ++r)
        o[mt][nd][r] += cc;
  }

  float* ob = out + (size_t)b * SEQ * DIM + h * 64;
#pragma unroll
  for (int mt = 0; mt < 4; ++mt)
#pragma unroll
    for (int r = 0; r < 4; ++r) {
      const int t = t0 + mt * 16 + quad * 4 + r;
#pragma unroll
      for (int nd = 0; nd < 4; ++nd)
        ob[(size_t)t * DIM + nd * 16 + l15] = o[mt][nd][r];
    }
}

extern "C" void kernel_launch(void* const* d_in, const int* in_sizes, int n_in,
                              void* d_out, int out_size, void* d_ws, size_t ws_size,
                              hipStream_t stream) {
  const float* x   = (const float*)d_in[0];
  const float* pos = (const float*)d_in[1];
  const float* Wq  = (const float*)d_in[2];
  const float* Wk  = (const float*)d_in[3];
  const float* Wv  = (const float*)d_in[4];
  float* out = (float*)d_out;

  // A_bf (33.5 MB) + Bp (6.3 MB) live in d_out (67 MB); both are dead before
  // pv_mfma fully overwrites d_out.
  ushort_t* Ab = (ushort_t*)d_out;
  ushort_t* Bp = (ushort_t*)((char*)d_out + 33554432);

  char* W = (char*)d_ws;
  ushort_t* q_bf   = (ushort_t*)(W);                  //  33,554,432 B  [b][h][t][d]
  ushort_t* k_bf   = (ushort_t*)(W + 33554432);       //  33,554,432 B
  ushort_t* vT_bf  = (ushort_t*)(W + 67108864);       //  33,554,432 B  [b][h][d][t]
  float*    part_l = (float*)  (W + 100663296);       //   8,388,608 B  (32 slots)
  float*    inv_lT = (float*)  (W + 167772160);       //     262,144 B

  prep_pack<<<dim3(9728), 256, 0, stream>>>(x, pos, Wq, Wk, Wv, Ab, Bp);
  qkv_mfma<<<dim3(768), 512, 0, stream>>>(Ab, Bp, q_bf, k_bf, vT_bf);
  stats_mfma<<<dim3(10, 32), 256, 0, stream>>>(q_bf, k_bf, part_l);
  merge_kernel<<<dim3(SEQ * SEQ / 256), 256, 0, stream>>>(part_l, inv_lT);
  pv_mfma<<<dim3(1024), 256, 0, stream>>>(q_bf, k_bf, vT_bf, inv_lT, out);
}

// Round 8
// 321.049 us; speedup vs baseline: 1.1011x; 1.0086x over previous
//
#include <hip/hip_runtime.h>

constexpr int SEQ = 256;
constexpr int DIM = 1024;
constexpr float SCALE = 0.0625f;  // 1/sqrt(256)

typedef __attribute__((ext_vector_type(8))) short bf16x8;
typedef __attribute__((ext_vector_type(4))) float f32x4;
typedef unsigned short ushort_t;
typedef unsigned int uint_t;

__device__ __forceinline__ void gld_lds16(const void* g, void* l) {
  __builtin_amdgcn_global_load_lds(
      (const __attribute__((address_space(1))) unsigned int*)g,
      (__attribute__((address_space(3))) unsigned int*)l, 16, 0, 0);
}

__device__ __forceinline__ ushort_t f2bf(float f) {  // round-to-nearest-even
  uint_t u = __float_as_uint(f);
  return (ushort_t)((u + 0x7fffu + ((u >> 16) & 1u)) >> 16);
}

__device__ __forceinline__ float bf2f(ushort_t h) {
  return __uint_as_float(((uint_t)h) << 16);
}

// ---------------- prep_pack: fused prep_a (blocks 0..8191) + pack_w (8192..9727) ------
__global__ __launch_bounds__(256)
void prep_pack(const float* __restrict__ x, const float* __restrict__ pos,
               const float* __restrict__ Wq, const float* __restrict__ Wk,
               const float* __restrict__ Wv,
               ushort_t* __restrict__ Ab, ushort_t* __restrict__ Bp) {
  const int bid = (int)blockIdx.x;
  if (bid < 8192) {
    const size_t idx = ((size_t)bid * 256 + threadIdx.x) * 8;
    const int m = (int)(idx >> 10), k = (int)(idx & 1023);
    float4 x0 = *(const float4*)(x + idx);
    float4 x1 = *(const float4*)(x + idx + 4);
    const float* pp = pos + ((size_t)(m & 255) << 10) + k;
    float4 p0 = *(const float4*)pp;
    float4 p1 = *(const float4*)(pp + 4);
    uint_t w0 = (uint_t)f2bf(x0.x + p0.x) | ((uint_t)f2bf(x0.y + p0.y) << 16);
    uint_t w1 = (uint_t)f2bf(x0.z + p0.z) | ((uint_t)f2bf(x0.w + p0.w) << 16);
    uint_t w2 = (uint_t)f2bf(x1.x + p1.x) | ((uint_t)f2bf(x1.y + p1.y) << 16);
    uint_t w3 = (uint_t)f2bf(x1.z + p1.z) | ((uint_t)f2bf(x1.w + p1.w) << 16);
    *(uint4*)&Ab[idx] = make_uint4(w0, w1, w2, w3);
  } else {
    const int pid = bid - 8192;                 // 0..1535
    const int z = pid >> 9;                     // 0..2
    const int rem = pid & 511;
    const int by = rem >> 2, bx = rem & 3;
    const float* W = (z == 0) ? Wq : (z == 1) ? Wk : Wv;
    const int n  = bx * 256 + threadIdx.x;
    const int k8 = by * 8;
    uint_t h[8];
#pragma unroll
    for (int i = 0; i < 8; ++i) h[i] = f2bf(W[(size_t)(k8 + i) * DIM + n]);
    uint_t hp[4];
#pragma unroll
    for (int j = 0; j < 4; ++j) hp[j] = h[2 * j] | (h[2 * j + 1] << 16);
    const int np = z * 1024 + n;
    const int nb = np >> 8, nl = np & 255;
    const int kc = k8 >> 6, kk = k8 & 63;
    size_t base = (((size_t)nb * 16 + kc) * 256 + nl) * 64 + kk;
    *(uint4*)&Bp[base] = make_uint4(hp[0], hp[1], hp[2], hp[3]);
  }
}

// ---------------- qkv: 256x256 tile, BK=64, 8 waves, counted lgkm/vmcnt pipeline ------
// R5-proven: 5-phase counted schedule + XCD-aware block remap (FETCH 143->95 MB).
__global__ __launch_bounds__(512, 2)
void qkv_mfma(const ushort_t* __restrict__ Ab, const ushort_t* __restrict__ Bp,
              ushort_t* __restrict__ q_bf, ushort_t* __restrict__ k_bf,
              ushort_t* __restrict__ vT_bf) {
  const int id = (int)blockIdx.x;       // 0..767
  const int q8 = id >> 3;               // 0..95
  const int nb = q8 % 12;               // fastest within an XCD's chunk
  const int mb = (id & 7) * 8 + q8 / 12;  // xcd owns mb in [xcd*8, xcd*8+8)
  const int tid = (int)threadIdx.x;
  const int wave = tid >> 6, lane = tid & 63;
  const int wm = wave >> 2, wn = wave & 3;
  const int l15 = lane & 15, quad = lane >> 4;

  __shared__ ushort_t smem[65536];  // buf c: A @ c*32768, B @ c*32768+16384 (ushorts)

  const int r8 = lane >> 3;
  const int lc8 = ((lane & 7) ^ r8) * 8;
  const size_t a_row = ((size_t)(mb * 256 + wave * 8 + r8)) << 10;
  const size_t b_row = ((size_t)((nb * 16) * 256 + wave * 8 + r8)) << 6;
  const int wb = wave * 512;

#define SA(q, tt, c) gld_lds16(Ab + a_row + ((size_t)(q) << 16) + (size_t)(tt) * 64 + lc8, \
                               smem + (c) * 32768 + (q) * 4096 + wb)
#define SB(q, tt, c) gld_lds16(Bp + b_row + (size_t)(tt) * 16384 + (q) * 4096 + lc8, \
                               smem + (c) * 32768 + 16384 + (q) * 4096 + wb)

  const int swz = l15 & 7;
  const int cko0 = (quad ^ swz) * 8;
  const int cko1 = ((4 + quad) ^ swz) * 8;
  const int arow0 = (wm * 128 + l15) * 64;
  const int brow0 = (wn * 64 + l15) * 64;

  f32x4 acc[8][4] = {};
  bf16x8 af[4][2], bf[4][2];

#define LDA_II(IH, ii) do { \
    const int ro = arow0 + ((IH) * 64 + (ii) * 16) * 64; \
    af[ii][0] = *(const bf16x8*)&Ac[ro + cko0]; \
    af[ii][1] = *(const bf16x8*)&Ac[ro + cko1]; } while (0)
#define LDB_J(J) do { const int ro = brow0 + (J) * 1024; \
    bf[J][0] = *(const bf16x8*)&Bc[ro + cko0]; \
    bf[J][1] = *(const bf16x8*)&Bc[ro + cko1]; } while (0)
#define MMQ(IH, II0, II1, J0) do { \
    _Pragma("unroll") for (int ks = 0; ks < 2; ++ks) \
    _Pragma("unroll") for (int ii = (II0); ii < (II1); ++ii) \
    _Pragma("unroll") for (int jj = 0; jj < 2; ++jj) \
      acc[(IH) * 4 + ii][(J0) + jj] = __builtin_amdgcn_mfma_f32_16x16x32_bf16( \
          af[ii][ks], bf[(J0) + jj][ks], acc[(IH) * 4 + ii][(J0) + jj], 0, 0, 0); \
    } while (0)

  SA(0, 0, 0); SA(2, 0, 0); SB(0, 0, 0); SB(1, 0, 0); SB(2, 0, 0); SB(3, 0, 0);
  SA(1, 0, 0); SA(3, 0, 0);
  SB(0, 1, 1); SB(1, 1, 1); SA(0, 1, 1); SA(2, 1, 1);
  asm volatile("s_waitcnt vmcnt(6)" ::: "memory");
  __builtin_amdgcn_s_barrier();

  for (int t = 0; t < 16; ++t) {
    const int cur = t & 1, nxt = cur ^ 1;
    const int tn  = (t < 15) ? t + 1 : 15;
    const int tn2 = (t < 14) ? t + 2 : 15;
    const ushort_t* Ac = &smem[cur * 32768];
    const ushort_t* Bc = Ac + 16384;
    // P0
    LDA_II(0, 0); LDA_II(0, 1); LDA_II(0, 2); LDA_II(0, 3);
    LDB_J(0); LDB_J(1);
    SB(2, tn, nxt); SB(3, tn, nxt);
    __builtin_amdgcn_s_barrier();
    // P1
    LDB_J(2); LDB_J(3);
    SA(1, tn, nxt); SA(3, tn, nxt);
    asm volatile("s_waitcnt lgkmcnt(4)" ::: "memory");
    __builtin_amdgcn_s_setprio(1);
    MMQ(0, 0, 4, 0);
    __builtin_amdgcn_s_setprio(0);
    asm volatile("s_waitcnt vmcnt(8)" ::: "memory");
    __builtin_amdgcn_s_barrier();
    // P2
    asm volatile("s_waitcnt lgkmcnt(0)" ::: "memory");
    __builtin_amdgcn_s_setprio(1);
    MMQ(0, 0, 2, 2);
    __builtin_amdgcn_s_setprio(0);
    LDA_II(1, 0); LDA_II(1, 1);
    __builtin_amdgcn_s_setprio(1);
    MMQ(0, 2, 4, 2);
    __builtin_amdgcn_s_setprio(0);
    LDA_II(1, 2); LDA_II(1, 3);
    __builtin_amdgcn_s_barrier();
    // P3
    SB(0, tn2, cur); SB(1, tn2, cur);
    asm volatile("s_waitcnt lgkmcnt(0)" ::: "memory");
    __builtin_amdgcn_s_setprio(1);
    MMQ(1, 0, 4, 2);
    __builtin_amdgcn_s_setprio(0);
    __builtin_amdgcn_s_barrier();
    // P4
    SA(0, tn2, cur); SA(2, tn2, cur);
    __builtin_amdgcn_s_setprio(1);
    MMQ(1, 0, 4, 0);
    __builtin_amdgcn_s_setprio(0);
    asm volatile("s_waitcnt vmcnt(6)" ::: "memory");
    __builtin_amdgcn_s_barrier();
  }

  asm volatile("s_waitcnt vmcnt(0)" ::: "memory");
  const int wq = nb >> 2;
  const int h  = (nb & 3) * 4 + wn;
  if (wq < 2) {
    ushort_t* base = ((wq == 0) ? q_bf : k_bf) + (size_t)(mb * 16 + h) * (SEQ * 64);
    const int tb = wm * 128 + quad * 4;
#pragma unroll
    for (int i = 0; i < 8; ++i)
#pragma unroll
      for (int j = 0; j < 4; ++j) {
        const int d = j * 16 + l15;
#pragma unroll
        for (int r = 0; r < 4; ++r)
          base[(size_t)(tb + i * 16 + r) * 64 + d] = f2bf(acc[i][j][r]);
      }
  } else {
    __builtin_amdgcn_s_barrier();
    ushort_t* L = &smem[wave * 4608];
    ushort_t* vbase = vT_bf + (size_t)(mb * 16 + h) * (64 * SEQ) + wm * 128;
    const int tc = (lane & 7) * 8;
#pragma unroll
    for (int g = 0; g < 2; ++g) {
#pragma unroll
      for (int ii = 0; ii < 4; ++ii)
#pragma unroll
        for (int j = 0; j < 4; ++j) {
          f32x4 v = acc[g * 4 + ii][j];
          uint_t lo = (uint_t)f2bf(v[0]) | ((uint_t)f2bf(v[1]) << 16);
          uint_t hi = (uint_t)f2bf(v[2]) | ((uint_t)f2bf(v[3]) << 16);
          *(uint2*)&L[(j * 16 + l15) * 72 + ii * 16 + quad * 4] = make_uint2(lo, hi);
        }
#pragma unroll
      for (int u = 0; u < 8; ++u) {
        const int d = u * 8 + r8;
        uint4 val = *(const uint4*)&L[d * 72 + tc];
        *(uint4*)&vbase[(size_t)d * SEQ + g * 64 + tc] = val;
      }
    }
  }
#undef SA
#undef SB
#undef LDA_II
#undef LDB_J
#undef MMQ
}

// ---------------- stats: partial l[t,s], 32 bh per block via cross-wave LDS reduce ----
__global__ __launch_bounds__(256)
void stats_mfma(const ushort_t* __restrict__ qb, const ushort_t* __restrict__ kb,
                float* __restrict__ part_l) {
  const int p = blockIdx.x, g = blockIdx.y;
  int tt, ss;
  if (p < 4) { tt = p; ss = p; }
  else {
    const int idx = p - 4;
    tt = (idx < 3) ? 0 : (idx < 5) ? 1 : 2;
    ss = (idx < 3) ? idx + 1 : (idx < 5) ? idx - 1 : 3;
  }
  const bool diag = (p < 4);
  const int tid = threadIdx.x, wave = tid >> 6, lane = tid & 63;
  const int l15 = lane & 15, quad = lane >> 4;

  __shared__ __attribute__((aligned(16))) float red[4][64 * 68];

  f32x4 lacc[4][4] = {};

  for (int i4 = 0; i4 < 8; ++i4) {
    const int bp = g * 32 + wave * 8 + i4;
    const int bh = (bp & 63) * 16 + (bp >> 6);
    const ushort_t* qt = qb + (size_t)bh * (SEQ * 64) + (size_t)(tt * 64) * 64;
    const ushort_t* kt = kb + (size_t)bh * (SEQ * 64) + (size_t)(ss * 64) * 64;
    bf16x8 aq[4][2], bk[4][2];
#pragma unroll
    for (int m = 0; m < 4; ++m)
#pragma unroll
      for (int ks = 0; ks < 2; ++ks) {
        aq[m][ks] = *(const bf16x8*)&qt[(m * 16 + l15) * 64 + ks * 32 + quad * 8];
        bk[m][ks] = *(const bf16x8*)&kt[(m * 16 + l15) * 64 + ks * 32 + quad * 8];
      }
    f32x4 sf[4][4] = {};
#pragma unroll
    for (int ks = 0; ks < 2; ++ks)
#pragma unroll
      for (int m = 0; m < 4; ++m)
#pragma unroll
        for (int n = 0; n < 4; ++n)
          sf[m][n] = __builtin_amdgcn_mfma_f32_16x16x32_bf16(aq[m][ks], bk[n][ks], sf[m][n], 0, 0, 0);
#pragma unroll
    for (int m = 0; m < 4; ++m)
#pragma unroll
      for (int n = 0; n < 4; ++n)
#pragma unroll
        for (int r = 0; r < 4; ++r) {
          float e = __expf(sf[m][n][r] * SCALE);
          if (diag) {
            const int t = tt * 64 + m * 16 + quad * 4 + r;
            const int s = ss * 64 + n * 16 + l15;
            e = (s > t) ? e : 1.0f;
          }
          lacc[m][n][r] += e;
        }
  }
  float* R = red[wave];
#pragma unroll
  for (int m = 0; m < 4; ++m)
#pragma unroll
    for (int r = 0; r < 4; ++r) {
      const int row = m * 16 + quad * 4 + r;
#pragma unroll
      for (int n = 0; n < 4; ++n)
        R[row * 68 + n * 16 + l15] = lacc[m][n][r];
    }
  __syncthreads();
  const int trow = tid >> 2, c0 = (tid & 3) * 16;
  const float* r0 = &red[0][trow * 68 + c0];
  const float* r1 = &red[1][trow * 68 + c0];
  const float* r2 = &red[2][trow * 68 + c0];
  const float* r3 = &red[3][trow * 68 + c0];
  float* pl = part_l + (size_t)g * (SEQ * SEQ) + (size_t)(tt * 64 + trow) * SEQ + ss * 64 + c0;
#pragma unroll
  for (int c = 0; c < 16; c += 4) {
    float4 s0 = *(const float4*)&r0[c];
    float4 s1 = *(const float4*)&r1[c];
    float4 s2 = *(const float4*)&r2[c];
    float4 s3 = *(const float4*)&r3[c];
    float4 o;
    o.x = (s0.x + s1.x) + (s2.x + s3.x);
    o.y = (s0.y + s1.y) + (s2.y + s3.y);
    o.z = (s0.z + s1.z) + (s2.z + s3.z);
    o.w = (s0.w + s1.w) + (s2.w + s3.w);
    *(float4*)&pl[c] = o;
  }
}

// ---------------- merge: sum 32 slots -> inv_l[t][s] ([t][s] layout, coalesced) ------
__global__ __launch_bounds__(256)
void merge_kernel(const float* __restrict__ part_l, float* __restrict__ inv_l) {
  const int i = blockIdx.x * 256 + threadIdx.x;  // t*256+s
  const int t = i >> 8, s = i & 255;
  float invv;
  if (s <= t) invv = 1.0f / 1024.0f;
  else {
    const float* p = part_l + i;
    float a0 = 0.f, a1 = 0.f, a2 = 0.f, a3 = 0.f,
          a4 = 0.f, a5 = 0.f, a6 = 0.f, a7 = 0.f;
    for (int g = 0; g < 32; g += 8) {
      const float* q = p + ((size_t)g << 16);
      a0 += q[0ull << 16]; a1 += q[1ull << 16]; a2 += q[2ull << 16]; a3 += q[3ull << 16];
      a4 += q[4ull << 16]; a5 += q[5ull << 16]; a6 += q[6ull << 16]; a7 += q[7ull << 16];
    }
    invv = 1.0f / (((a0 + a1) + (a2 + a3)) + ((a4 + a5) + (a6 + a7)));
  }
  inv_l[i] = invv;   // [t][s] layout: direct coalesced store
}

// ---------------- pv: 2 bh per block, reversed wave roles on 2nd bh (load balance) ----
// Wave w computes (4-w) tiles for bh0 (tb=w) and (1+w) tiles for bh1 (tb=3-w) = 5 each
// (was worst-case 8). Both colsums precomputed -> no barrier between the two bh.
// inv_l is [t][s]: one aligned float4 covers the 4 consecutive s of each (ms,nt,quad).
__global__ __launch_bounds__(256)
void pv_mfma(const ushort_t* __restrict__ qb, const ushort_t* __restrict__ kb,
             const ushort_t* __restrict__ vtb, const float* __restrict__ inv_l,
             float* __restrict__ out) {
  const int blk = (int)blockIdx.x;     // 0..511
  const int tid = threadIdx.x, wave = tid >> 6, lane = tid & 63;
  const int l15 = lane & 15, quad = lane >> 4;

  __shared__ ushort_t Plds[4][64][72];
  __shared__ float csumL[2][4][64];    // csumL[vb][s-tile][d]
  ushort_t (*Pw)[72] = Plds[wave];

  // colsums for both bh up front (single barrier)
#pragma unroll
  for (int vb = 0; vb < 2; ++vb) {
    const ushort_t* vr = vtb + (size_t)(blk * 2 + vb) * (64 * SEQ)
                       + (size_t)lane * SEQ + wave * 64;
    float s = 0.f;
#pragma unroll
    for (int j = 0; j < 8; ++j) {
      bf16x8 v8 = *(const bf16x8*)&vr[j * 8];
#pragma unroll
      for (int e = 0; e < 8; ++e) s += bf2f((ushort_t)v8[e]);
    }
    csumL[vb][wave][lane] = s;
  }
  __syncthreads();

  for (int vb = 0; vb < 2; ++vb) {
    const int bh = blk * 2 + vb;
    const int b = bh >> 4, h = bh & 15;
    const int tb = vb ? (3 - wave) : wave;    // wave's t-block for this bh
    const int t0 = tb * 64;

    const ushort_t* qq = qb + (size_t)bh * (SEQ * 64);
    const ushort_t* kk = kb + (size_t)bh * (SEQ * 64);
    const ushort_t* vv = vtb + (size_t)bh * (64 * SEQ);

    bf16x8 qf[4][2];
#pragma unroll
    for (int nt = 0; nt < 4; ++nt)
#pragma unroll
      for (int ks = 0; ks < 2; ++ks)
        qf[nt][ks] = *(const bf16x8*)&qq[(t0 + nt * 16 + l15) * 64 + ks * 32 + quad * 8];

    f32x4 o[4][4] = {};

    for (int sc = tb; sc < 4; ++sc) {
      bf16x8 kf[4][2];
#pragma unroll
      for (int ms = 0; ms < 4; ++ms)
#pragma unroll
        for (int ks = 0; ks < 2; ++ks)
          kf[ms][ks] = *(const bf16x8*)&kk[(sc * 64 + ms * 16 + l15) * 64 + ks * 32 + quad * 8];
      f32x4 sf[4][4] = {};
#pragma unroll
      for (int ks = 0; ks < 2; ++ks)
#pragma unroll
        for (int ms = 0; ms < 4; ++ms)
#pragma unroll
          for (int nt = 0; nt < 4; ++nt)
            sf[ms][nt] = __builtin_amdgcn_mfma_f32_16x16x32_bf16(kf[ms][ks], qf[nt][ks], sf[ms][nt], 0, 0, 0);
      const bool dg = (sc == tb);
      const int t = t0 + l15;
#pragma unroll
      for (int ms = 0; ms < 4; ++ms)
#pragma unroll
        for (int nt = 0; nt < 4; ++nt) {
          const int sb = sc * 64 + ms * 16 + quad * 4;
          const int tc = t + nt * 16;
          const float4 iv = *(const float4*)&inv_l[(size_t)tc * SEQ + sb];
          ushort_t pb[4];
#pragma unroll
          for (int r = 0; r < 4; ++r) {
            const int s = sb + r;
            float e = __expf(sf[ms][nt][r] * SCALE);
            if (dg) e = (s > tc) ? e : 1.0f;
            const float ivr = (r == 0) ? iv.x : (r == 1) ? iv.y : (r == 2) ? iv.z : iv.w;
            pb[r] = f2bf(e * ivr);
          }
          uint_t lo = (uint_t)pb[0] | ((uint_t)pb[1] << 16);
          uint_t hi = (uint_t)pb[2] | ((uint_t)pb[3] << 16);
          *(uint2*)&Pw[nt * 16 + l15][ms * 16 + quad * 4] = make_uint2(lo, hi);
        }

      bf16x8 vf[4][2], pf[4][2];
#pragma unroll
      for (int nd = 0; nd < 4; ++nd)
#pragma unroll
        for (int ks = 0; ks < 2; ++ks)
          vf[nd][ks] = *(const bf16x8*)&vv[(nd * 16 + l15) * SEQ + sc * 64 + ks * 32 + quad * 8];
#pragma unroll
      for (int mt = 0; mt < 4; ++mt)
#pragma unroll
        for (int ks = 0; ks < 2; ++ks)
          pf[mt][ks] = *(const bf16x8*)&Pw[mt * 16 + l15][ks * 32 + quad * 8];
#pragma unroll
      for (int ks = 0; ks < 2; ++ks)
#pragma unroll
        for (int mt = 0; mt < 4; ++mt)
#pragma unroll
          for (int nd = 0; nd < 4; ++nd)
            o[mt][nd] = __builtin_amdgcn_mfma_f32_16x16x32_bf16(pf[mt][ks], vf[nd][ks], o[mt][nd], 0, 0, 0);
    }

    // constant-P prefix: O[t,d] += (1/1024) * sum_{s < tb*64} vT[d][s]
#pragma unroll
    for (int nd = 0; nd < 4; ++nd) {
      const int d = nd * 16 + l15;
      float pref = 0.f;
      for (int w2 = 0; w2 < tb; ++w2) pref += csumL[vb][w2][d];
      const float cc = pref * (1.0f / 1024.0f);
#pragma unroll
      for (int mt = 0; mt < 4; ++mt)
#pragma unroll
        for (int r = 0; r < 4; ++r)
          o[mt][nd][r] += cc;
    }

    float* ob = out + (size_t)b * SEQ * DIM + h * 64;
#pragma unroll
    for (int mt = 0; mt < 4; ++mt)
#pragma unroll
      for (int r = 0; r < 4; ++r) {
        const int t = t0 + mt * 16 + quad * 4 + r;
#pragma unroll
        for (int nd = 0; nd < 4; ++nd)
          ob[(size_t)t * DIM + nd * 16 + l15] = o[mt][nd][r];
      }
  }
}

extern "C" void kernel_launch(void* const* d_in, const int* in_sizes, int n_in,
                              void* d_out, int out_size, void* d_ws, size_t ws_size,
                              hipStream_t stream) {
  const float* x   = (const float*)d_in[0];
  const float* pos = (const float*)d_in[1];
  const float* Wq  = (const float*)d_in[2];
  const float* Wk  = (const float*)d_in[3];
  const float* Wv  = (const float*)d_in[4];
  float* out = (float*)d_out;

  // A_bf (33.5 MB) + Bp (6.3 MB) live in d_out (67 MB); both are dead before
  // pv_mfma fully overwrites d_out.
  ushort_t* Ab = (ushort_t*)d_out;
  ushort_t* Bp = (ushort_t*)((char*)d_out + 33554432);

  char* W = (char*)d_ws;
  ushort_t* q_bf   = (ushort_t*)(W);                  //  33,554,432 B  [b][h][t][d]
  ushort_t* k_bf   = (ushort_t*)(W + 33554432);       //  33,554,432 B
  ushort_t* vT_bf  = (ushort_t*)(W + 67108864);       //  33,554,432 B  [b][h][d][t]
  float*    part_l = (float*)  (W + 100663296);       //   8,388,608 B  (32 slots)
  float*    inv_l  = (float*)  (W + 167772160);       //     262,144 B  [t][s]

  prep_pack<<<dim3(9728), 256, 0, stream>>>(x, pos, Wq, Wk, Wv, Ab, Bp);
  qkv_mfma<<<dim3(768), 512, 0, stream>>>(Ab, Bp, q_bf, k_bf, vT_bf);
  stats_mfma<<<dim3(10, 32), 256, 0, stream>>>(q_bf, k_bf, part_l);
  merge_kernel<<<dim3(SEQ * SEQ / 256), 256, 0, stream>>>(part_l, inv_l);
  pv_mfma<<<dim3(512), 256, 0, stream>>>(q_bf, k_bf, vT_bf, inv_l, out);
}